// Round 11
// baseline (108.082 us; speedup 1.0000x reference)
//
#include <hip/hip_runtime.h>
#include <hip/hip_bf16.h>

typedef __attribute__((ext_vector_type(8))) short short8;
typedef __attribute__((ext_vector_type(4))) float floatx4;

#define AS1(p) ((const __attribute__((address_space(1))) void*)(p))
#define AS3(p) ((__attribute__((address_space(3))) void*)(p))

__device__ __forceinline__ float bf_lo(unsigned u) { return __uint_as_float(u << 16); }
__device__ __forceinline__ float bf_hi(unsigned u) { return __uint_as_float(u & 0xffff0000u); }

// ---------------------------------------------------------------- unified prep v3: transpose+cast
// Block = 256 src-rows (full c/k) x 64 dst-rows. Stores are FULL 512B output rows
// (wave = 2 rows = 1KB contiguous). LDS f32 [256][68] + col-XOR swizzle -> 2-way reads (free).
// Ranges: [0,1024) feats NCHW->NHWC; [1024,1808) W1 permute; [1808,1872) W2 transpose.
__global__ __launch_bounds__(512) void prep_kernel(
    const float* __restrict__ feats, const float* __restrict__ W1, const float* __restrict__ W2,
    __hip_bfloat16* __restrict__ featsT, __hip_bfloat16* __restrict__ W1T,
    __hip_bfloat16* __restrict__ W2T)
{
    __shared__ float tile[256][68];   // 69,632 B; row = 272 B (16B-aligned)
    const int t = threadIdx.x;
    const int w = t >> 6, l = t & 63;
    const int bid = blockIdx.x;

    const float* src;
    __hip_bfloat16* dst;
    size_t sstride, dstride;

    if (bid < 1024) {
        // feats[b][c][hw] -> featsT[b][hw][c]; src row=c (stride 16384), 64 hw cols
        const int b = bid >> 8, hwt = bid & 255;
        src = feats + (size_t)b * 256 * 16384 + hwt * 64;
        sstride = 16384;
        dst = featsT + ((size_t)b * 16384 + hwt * 64) * 256;
        dstride = 256;
    } else if (bid < 1808) {
        // W1[(c*49+bin)][n] -> W1T[n][bin*256+c]; src row=c (stride 49*1024), 64 n cols
        const int r = bid - 1024;
        const int bin = r >> 4, nt = r & 15;
        src = W1 + (size_t)bin * 1024 + nt * 64;
        sstride = 49 * 1024;
        dst = W1T + (size_t)(nt * 64) * 12544 + bin * 256;
        dstride = 12544;
    } else {
        // W2[k][n] -> W2T[n][k]; src row=k (256-window), 64 n cols
        const int r = bid - 1808;
        const int kt = r >> 4, nt = r & 15;
        src = W2 + (size_t)(kt * 256) * 1024 + nt * 64;
        sstride = 1024;
        dst = W2T + (size_t)(nt * 64) * 1024 + kt * 256;
        dstride = 1024;
    }

    // load: 8 iters; src-row r = i*32 + w*4 + (l>>4); col4 = (l&15)*4 (float4)
    #pragma unroll
    for (int i = 0; i < 8; ++i) {
        const int r  = i * 32 + w * 4 + (l >> 4);
        const int c4 = (l & 15) * 4;
        const float4 v = *(const float4*)(src + (size_t)r * sstride + c4);
        *(float4*)&tile[r][c4 ^ (((r >> 3) & 15) << 2)] = v;
    }
    __syncthreads();

    // store: 4 iters; dst-row d = i*16 + w*2 + (l>>5); c8 = (l&31)*8 -> uint4 (16B)
    #pragma unroll
    for (int i = 0; i < 4; ++i) {
        const int d  = i * 16 + w * 2 + (l >> 5);
        const int a  = l & 31;
        const int c8 = a * 8;
        const int dsw = d ^ ((a & 15) << 2);   // inverse of the load-side col swizzle
        union { __hip_bfloat16 h[8]; uint4 u; } o;
        #pragma unroll
        for (int j = 0; j < 8; ++j)
            o.h[j] = __float2bfloat16(tile[c8 + j][dsw]);
        *(uint4*)(dst + (size_t)d * dstride + c8) = o.u;
    }
}

// ---------------------------------------------------------------- ROI align from NHWC bf16 (v4)
__global__ __launch_bounds__(256) void roi_kernel4(
    const __hip_bfloat16* __restrict__ featsT, const float* __restrict__ boxes,
    __hip_bfloat16* __restrict__ pooled)
{
    __shared__ int   sy0[14], sy1[14], sx0[14], sx1[14];
    __shared__ float sly[14], svy[14], slx[14], svx[14];
    const int tid  = threadIdx.x;
    const int bn   = blockIdx.x >> 1;
    const int half = blockIdx.x & 1;
    if (tid < 28) {
        const int  i   = tid % 14;
        const bool isx = tid >= 14;
        const float lo = boxes[bn * 4 + (isx ? 0 : 1)] * 0.25f;
        const float hi = boxes[bn * 4 + (isx ? 2 : 3)] * 0.25f;
        const float szb = fmaxf(hi - lo, 1.0f) * (1.0f / 7.0f);
        const float coord = lo + szb * ((i + 0.5f) * 0.5f);
        const float valid = (coord > -1.0f && coord < 128.0f) ? 1.0f : 0.0f;
        const float cc = fminf(fmaxf(coord, 0.0f), 127.0f);
        const int i0 = (int)floorf(cc);
        const int i1 = min(i0 + 1, 127);
        const float l = cc - (float)i0;
        if (isx) { sx0[i] = i0; sx1[i] = i1; slx[i] = l; svx[i] = valid; }
        else     { sy0[i] = i0; sy1[i] = i1; sly[i] = l; svy[i] = valid; }
    }
    __syncthreads();
    const int wave = tid >> 6;
    const int lane = tid & 63;
    const int sub  = lane >> 5;
    const int co   = lane & 31;
    const int b    = bn >> 8;
    const __hip_bfloat16* fb = featsT + (size_t)b * 4194304 + co * 8;
    __hip_bfloat16* po = pooled + (size_t)bn * 12544 + co * 8;

    const int pstart = (half ? 12 : 0) + wave;
    const int pend   = half ? 25 : 12;
    for (int p = pstart; p < pend; p += 4) {
        int bin = 2 * p + sub;
        if (bin > 48) bin = 48;
        const int ph = (bin * 37) >> 8;
        const int pw = bin - ph * 7;
        float s0 = 0.f, s1 = 0.f, s2 = 0.f, s3 = 0.f;
        float s4 = 0.f, s5 = 0.f, s6 = 0.f, s7 = 0.f;
        #pragma unroll
        for (int sy = 0; sy < 2; ++sy) {
            const int iy = ph * 2 + sy;
            const int y0 = sy0[iy], y1 = sy1[iy];
            const float ly = sly[iy], wy = svy[iy];
            const float hy = 1.f - ly;
            #pragma unroll
            for (int sx = 0; sx < 2; ++sx) {
                const int ix = pw * 2 + sx;
                const int x0 = sx0[ix], x1 = sx1[ix];
                const float lx = slx[ix], wx = svx[ix];
                const float hx = 1.f - lx;
                const uint4 u00 = *(const uint4*)(fb + (((y0 << 7) + x0) * 256));
                const uint4 u01 = *(const uint4*)(fb + (((y0 << 7) + x1) * 256));
                const uint4 u10 = *(const uint4*)(fb + (((y1 << 7) + x0) * 256));
                const uint4 u11 = *(const uint4*)(fb + (((y1 << 7) + x1) * 256));
                const float wv  = wy * wx;
                const float w00 = hy * hx * wv, w01 = hy * lx * wv;
                const float w10 = ly * hx * wv, w11 = ly * lx * wv;
                s0 += w00 * bf_lo(u00.x) + w01 * bf_lo(u01.x) + w10 * bf_lo(u10.x) + w11 * bf_lo(u11.x);
                s1 += w00 * bf_hi(u00.x) + w01 * bf_hi(u01.x) + w10 * bf_hi(u10.x) + w11 * bf_hi(u11.x);
                s2 += w00 * bf_lo(u00.y) + w01 * bf_lo(u01.y) + w10 * bf_lo(u10.y) + w11 * bf_lo(u11.y);
                s3 += w00 * bf_hi(u00.y) + w01 * bf_hi(u01.y) + w10 * bf_hi(u10.y) + w11 * bf_hi(u11.y);
                s4 += w00 * bf_lo(u00.z) + w01 * bf_lo(u01.z) + w10 * bf_lo(u10.z) + w11 * bf_lo(u11.z);
                s5 += w00 * bf_hi(u00.z) + w01 * bf_hi(u01.z) + w10 * bf_hi(u10.z) + w11 * bf_hi(u11.z);
                s6 += w00 * bf_lo(u00.w) + w01 * bf_lo(u01.w) + w10 * bf_lo(u10.w) + w11 * bf_lo(u11.w);
                s7 += w00 * bf_hi(u00.w) + w01 * bf_hi(u01.w) + w10 * bf_hi(u10.w) + w11 * bf_hi(u11.w);
            }
        }
        union { __hip_bfloat16 h[8]; uint4 u; } o;
        o.h[0] = __float2bfloat16(s0 * 0.25f);
        o.h[1] = __float2bfloat16(s1 * 0.25f);
        o.h[2] = __float2bfloat16(s2 * 0.25f);
        o.h[3] = __float2bfloat16(s3 * 0.25f);
        o.h[4] = __float2bfloat16(s4 * 0.25f);
        o.h[5] = __float2bfloat16(s5 * 0.25f);
        o.h[6] = __float2bfloat16(s6 * 0.25f);
        o.h[7] = __float2bfloat16(s7 * 0.25f);
        *(uint4*)(po + bin * 256) = o.u;
    }
}

// ---------------------------------------------------------------- GEMM1: 256x256 tile, 8-phase,
// 3-bit XOR swizzle, XCD-exact z-map, vmcnt(4) before certifying barriers (phases 4/8).
__global__ __launch_bounds__(512, 2) void gemm1_8phase(
    const __hip_bfloat16* __restrict__ A,
    const __hip_bfloat16* __restrict__ BT,
    __hip_bfloat16* __restrict__ Cpart)
{
    constexpr int K = 12544;
    constexpr int KCHUNK = 896;
    constexpr int NKT = 14;
    constexpr int ITERS = 7;

    __shared__ char lds[131072];

    const int bid = blockIdx.x;
    const int xcd = bid & 7;
    const int sl  = bid >> 3;
    const int z   = xcd + 8 * (sl >> 4);
    if (z >= 14) return;
    const int tile = sl & 15;
    const int by = tile >> 2, bx = tile & 3;
    const int m0 = by << 8, n0 = bx << 8;
    const int k0 = z * KCHUNK;

    const int tid  = threadIdx.x;
    const int lane = tid & 63;
    const int wave = tid >> 6;
    const int wm   = wave >> 2;
    const int wn   = wave & 3;
    const int l15  = lane & 15;
    const int kq   = (lane >> 4) << 3;

    floatx4 acc[8][4] = {};
    short8 bf[4][2];

    auto stage = [&](const __hip_bfloat16* gsrc, int ldsoff) {
        #pragma unroll
        for (int j = 0; j < 2; ++j) {
            const int lin = j * 8192 + tid * 16;
            const int r   = lin >> 7;
            const int cs  = ((lin & 127) ^ ((r & 7) << 4)) >> 1;
            __builtin_amdgcn_global_load_lds(AS1(gsrc + (size_t)r * K + cs),
                                             AS3(lds + ldsoff + lin), 16, 0, 0);
        }
    };

#define PHASE(SLOT, MQ, FIRSTB, STAGE_STMT, VM)                                    \
    {                                                                               \
        if (FIRSTB) {                                                               \
            _Pragma("unroll")                                                       \
            for (int nf = 0; nf < 4; ++nf) {                                        \
                const int nl = wn * 64 + nf * 16 + l15;                             \
                const int bh = nl >> 7, br = nl & 127;                              \
                _Pragma("unroll")                                                   \
                for (int ks = 0; ks < 2; ++ks)                                      \
                    bf[nf][ks] = *(const short8*)(lds + (SLOT) * 65536 + 32768      \
                        + bh * 16384 + br * 128                                     \
                        + (((ks * 32 + kq) * 2) ^ ((br & 7) << 4)));                \
            }                                                                       \
        }                                                                           \
        short8 af[2][2];                                                            \
        _Pragma("unroll")                                                           \
        for (int mf = 0; mf < 2; ++mf) {                                            \
            const int ar = (MQ) * 32 + mf * 16 + l15;                               \
            _Pragma("unroll")                                                       \
            for (int ks = 0; ks < 2; ++ks)                                          \
                af[mf][ks] = *(const short8*)(lds + (SLOT) * 65536 + wm * 16384     \
                    + ar * 128 + (((ks * 32 + kq) * 2) ^ ((ar & 7) << 4)));         \
        }                                                                           \
        STAGE_STMT;                                                                 \
        __builtin_amdgcn_s_barrier();                                               \
        asm volatile("s_waitcnt lgkmcnt(0)" ::: "memory");                          \
        __builtin_amdgcn_s_setprio(1);                                              \
        _Pragma("unroll")                                                           \
        for (int mf = 0; mf < 2; ++mf)                                              \
            _Pragma("unroll")                                                       \
            for (int nf = 0; nf < 4; ++nf)                                          \
                _Pragma("unroll")                                                   \
                for (int ks = 0; ks < 2; ++ks)                                      \
                    acc[(MQ) * 2 + mf][nf] = __builtin_amdgcn_mfma_f32_16x16x32_bf16( \
                        af[mf][ks], bf[nf][ks], acc[(MQ) * 2 + mf][nf], 0, 0, 0);   \
        __builtin_amdgcn_s_setprio(0);                                              \
        if (VM) asm volatile("s_waitcnt vmcnt(4)" ::: "memory");                    \
        __builtin_amdgcn_s_barrier();                                               \
    }

    stage(BT + (size_t)n0 * K + k0,               32768);
    stage(BT + (size_t)(n0 + 128) * K + k0,       32768 + 16384);
    stage(A  + (size_t)m0 * K + k0,               0);
    stage(A  + (size_t)(m0 + 128) * K + k0,       16384);
    stage(BT + (size_t)n0 * K + k0 + 64,          65536 + 32768);
    stage(BT + (size_t)(n0 + 128) * K + k0 + 64,  65536 + 32768 + 16384);
    asm volatile("s_waitcnt vmcnt(4)" ::: "memory");
    __builtin_amdgcn_s_barrier();

    for (int it = 0; it < ITERS; ++it) {
        const int t1 = 2 * it + 1;
        int t2 = 2 * it + 2; if (t2 > NKT - 1) t2 = NKT - 1;
        int t3 = 2 * it + 3; if (t3 > NKT - 1) t3 = NKT - 1;
        PHASE(0, 0, true,  stage(A  + (size_t)m0 * K + k0 + t1 * 64,          65536),          0);
        PHASE(0, 1, false, stage(A  + (size_t)(m0 + 128) * K + k0 + t1 * 64,  65536 + 16384),  0);
        PHASE(0, 2, false, stage(BT + (size_t)n0 * K + k0 + t2 * 64,          32768),          0);
        PHASE(0, 3, false, stage(BT + (size_t)(n0 + 128) * K + k0 + t2 * 64,  32768 + 16384),  1);
        PHASE(1, 0, true,  stage(A  + (size_t)m0 * K + k0 + t2 * 64,          0),              0);
        PHASE(1, 1, false, stage(A  + (size_t)(m0 + 128) * K + k0 + t2 * 64,  16384),          0);
        PHASE(1, 2, false, stage(BT + (size_t)n0 * K + k0 + t3 * 64,          65536 + 32768),  0);
        PHASE(1, 3, false, stage(BT + (size_t)(n0 + 128) * K + k0 + t3 * 64,  65536 + 32768 + 16384), 1);
    }
#undef PHASE

    __hip_bfloat16* cp = Cpart + (size_t)z * (1024 * 1024) + (size_t)m0 * 1024 + n0;
    const int r4 = (lane >> 4) << 2;
    #pragma unroll
    for (int mi = 0; mi < 8; ++mi)
        #pragma unroll
        for (int nf = 0; nf < 4; ++nf)
            #pragma unroll
            for (int r = 0; r < 4; ++r)
                cp[(size_t)(wm * 128 + mi * 16 + r4 + r) * 1024 + wn * 64 + nf * 16 + l15] =
                    __float2bfloat16(acc[mi][nf][r]);
}

// ---------------------------------------------------------------- 128^2 GEMM (GEMM2), swizzled LDS
__global__ __launch_bounds__(256) void gemm_bf16_kernel(
    const __hip_bfloat16* __restrict__ A,
    const __hip_bfloat16* __restrict__ BT,
    __hip_bfloat16* __restrict__ Cpart,
    int Mdim, int Ndim, int K, int kChunk)
{
    __shared__ __hip_bfloat16 lsA[128 * 64];
    __shared__ __hip_bfloat16 lsB[128 * 64];
    const int tid  = threadIdx.x;
    const int lane = tid & 63;
    const int wave = tid >> 6;
    const int wrow = (wave >> 1) << 6;
    const int wcol = (wave & 1) << 6;
    const int m0 = blockIdx.y << 7;
    const int n0 = blockIdx.x << 7;
    const int k0 = blockIdx.z * kChunk;

    floatx4 acc[4][4] = {};

    const int strow = tid >> 3;
    const int scol  = ((tid & 7) ^ (strow & 7)) << 3;
    const __hip_bfloat16* aSrc = A  + (size_t)(m0 + strow) * K + k0 + scol;
    const __hip_bfloat16* bSrc = BT + (size_t)(n0 + strow) * K + k0 + scol;
    __hip_bfloat16* ldsA = lsA + tid * 8;
    __hip_bfloat16* ldsB = lsB + tid * 8;
    const size_t rowJump = (size_t)32 * K;

    const int row16 = lane & 15;
    const int kg    = (lane >> 4) << 3;
    const int nk = kChunk >> 6;
    for (int kk = 0; kk < nk; ++kk) {
        __syncthreads();
        #pragma unroll
        for (int g = 0; g < 4; ++g) {
            __builtin_amdgcn_global_load_lds(AS1(aSrc + g * rowJump), AS3(ldsA + g * 2048), 16, 0, 0);
            __builtin_amdgcn_global_load_lds(AS1(bSrc + g * rowJump), AS3(ldsB + g * 2048), 16, 0, 0);
        }
        __syncthreads();
        #pragma unroll
        for (int ks = 0; ks < 2; ++ks) {
            short8 af[4], bfr[4];
            #pragma unroll
            for (int m = 0; m < 4; ++m) {
                const int ar = wrow + m * 16 + row16;
                af[m] = *(const short8*)(lsA + ar * 64 + ((ks * 32 + kg) ^ ((ar & 7) << 3)));
            }
            #pragma unroll
            for (int n = 0; n < 4; ++n) {
                const int br = wcol + n * 16 + row16;
                bfr[n] = *(const short8*)(lsB + br * 64 + ((ks * 32 + kg) ^ ((br & 7) << 3)));
            }
            #pragma unroll
            for (int m = 0; m < 4; ++m)
                #pragma unroll
                for (int n = 0; n < 4; ++n)
                    acc[m][n] = __builtin_amdgcn_mfma_f32_16x16x32_bf16(af[m], bfr[n], acc[m][n], 0, 0, 0);
        }
        aSrc += 64; bSrc += 64;
    }
    __hip_bfloat16* cp = Cpart + (size_t)blockIdx.z * Mdim * Ndim + (size_t)m0 * Ndim + n0;
    const int r4 = (lane >> 4) << 2;
    #pragma unroll
    for (int m = 0; m < 4; ++m)
        #pragma unroll
        for (int n = 0; n < 4; ++n)
            #pragma unroll
            for (int r = 0; r < 4; ++r)
                cp[(size_t)(wrow + m * 16 + r4 + r) * Ndim + (wcol + n * 16 + row16)] =
                    __float2bfloat16(acc[m][n][r]);
}

// ---------------------------------------------------------------- splitK reduce + bias + ReLU -> bf16
__global__ __launch_bounds__(256) void reduce_relu_kernel(
    const __hip_bfloat16* __restrict__ part, const float* __restrict__ bias,
    __hip_bfloat16* __restrict__ out, int nsplit)
{
    const size_t MN = 1024 * 1024;
    const int idx = (blockIdx.x * 256 + threadIdx.x) * 8;
    float s[8] = {};
    for (int z = 0; z < nsplit; ++z) {
        const uint4 v = *(const uint4*)(part + z * MN + idx);
        s[0] += bf_lo(v.x); s[1] += bf_hi(v.x);
        s[2] += bf_lo(v.y); s[3] += bf_hi(v.y);
        s[4] += bf_lo(v.z); s[5] += bf_hi(v.z);
        s[6] += bf_lo(v.w); s[7] += bf_hi(v.w);
    }
    const int jb = idx & 1023;
    const floatx4 b0 = *(const floatx4*)(bias + jb);
    const floatx4 b1v = *(const floatx4*)(bias + jb + 4);
    union { __hip_bfloat16 h[8]; uint4 u; } o;
    #pragma unroll
    for (int i = 0; i < 4; ++i) {
        const float v0 = s[i] + b0[i];
        o.h[i] = __float2bfloat16(v0 > 0.0f ? v0 : 0.0f);
    }
    #pragma unroll
    for (int i = 0; i < 4; ++i) {
        const float v1 = s[4 + i] + b1v[i];
        o.h[4 + i] = __float2bfloat16(v1 > 0.0f ? v1 : 0.0f);
    }
    *(uint4*)(out + idx) = o.u;
}

// ---------------------------------------------------------------- block LN stats
__device__ inline void block_stats(float s, float ss, float* red, float& mean, float& rstd)
{
    #pragma unroll
    for (int o = 32; o > 0; o >>= 1) {
        s  += __shfl_down(s, o, 64);
        ss += __shfl_down(ss, o, 64);
    }
    const int wave = threadIdx.x >> 6;
    const int lane = threadIdx.x & 63;
    __syncthreads();
    if (lane == 0) { red[wave] = s; red[8 + wave] = ss; }
    __syncthreads();
    const float a = red[0] + red[1] + red[2] + red[3];
    const float b = red[8] + red[9] + red[10] + red[11];
    mean = a * (1.0f / 1024.0f);
    const float var = b * (1.0f / 1024.0f) - mean * mean;
    rstd = rsqrtf(var + 1e-5f);
}

// ---------------------------------------------------------------- splitK reduce2 (bf16) + bbox path + 2x LN
__global__ __launch_bounds__(256) void final_kernel(
    const __hip_bfloat16* __restrict__ part2, const float* __restrict__ b2,
    const float* __restrict__ boxes,
    const float* __restrict__ bboxW, const float* __restrict__ bboxb,
    const float* __restrict__ g1, const float* __restrict__ bb1,
    const float* __restrict__ g2, const float* __restrict__ bb2,
    float* __restrict__ out)
{
    __shared__ float red[16];
    const int row = blockIdx.x;
    const int j0 = threadIdx.x * 4;
    const size_t MN = 1024 * 1024;

    floatx4 h = *(const floatx4*)(b2 + j0);
    #pragma unroll
    for (int z = 0; z < 4; ++z) {
        const uint2 v = *(const uint2*)(part2 + z * MN + (size_t)row * 1024 + j0);
        h[0] += bf_lo(v.x); h[1] += bf_hi(v.x);
        h[2] += bf_lo(v.y); h[3] += bf_hi(v.y);
    }

    const float sc = 0.25f / 128.0f;
    const float nb0 = boxes[row * 4 + 0] * sc;
    const float nb1 = boxes[row * 4 + 1] * sc;
    const float nb2 = boxes[row * 4 + 2] * sc;
    const float nb3 = boxes[row * 4 + 3] * sc;

    floatx4 p = *(const floatx4*)(bboxb + j0);
    p += nb0 * *(const floatx4*)(bboxW + j0);
    p += nb1 * *(const floatx4*)(bboxW + 1024 + j0);
    p += nb2 * *(const floatx4*)(bboxW + 2048 + j0);
    p += nb3 * *(const floatx4*)(bboxW + 3072 + j0);

    float mean, rstd;
    block_stats(p[0] + p[1] + p[2] + p[3],
                p[0]*p[0] + p[1]*p[1] + p[2]*p[2] + p[3]*p[3], red, mean, rstd);
    const floatx4 pg = *(const floatx4*)(g1 + j0);
    const floatx4 pb = *(const floatx4*)(bb1 + j0);
    floatx4 x;
    #pragma unroll
    for (int i = 0; i < 4; ++i)
        x[i] = h[i] + ((p[i] - mean) * rstd * pg[i] + pb[i]);

    block_stats(x[0] + x[1] + x[2] + x[3],
                x[0]*x[0] + x[1]*x[1] + x[2]*x[2] + x[3]*x[3], red, mean, rstd);
    const floatx4 og = *(const floatx4*)(g2 + j0);
    const floatx4 ob = *(const floatx4*)(bb2 + j0);
    floatx4 o;
    #pragma unroll
    for (int i = 0; i < 4; ++i)
        o[i] = (x[i] - mean) * rstd * og[i] + ob[i];
    *(floatx4*)(out + (size_t)row * 1024 + j0) = o;
}

// ---------------------------------------------------------------- launch
extern "C" void kernel_launch(void* const* d_in, const int* in_sizes, int n_in,
                              void* d_out, int out_size, void* d_ws, size_t ws_size,
                              hipStream_t stream)
{
    const float* feats = (const float*)d_in[0];
    const float* boxes = (const float*)d_in[1];
    const float* W1    = (const float*)d_in[3];
    const float* b1    = (const float*)d_in[4];
    const float* W2    = (const float*)d_in[5];
    const float* b2    = (const float*)d_in[6];
    const float* bboxW = (const float*)d_in[7];
    const float* bboxb = (const float*)d_in[8];
    const float* g1    = (const float*)d_in[9];
    const float* bb1   = (const float*)d_in[10];
    const float* g2    = (const float*)d_in[11];
    const float* bb2   = (const float*)d_in[12];
    float* out = (float*)d_out;

    char* ws = (char*)d_ws;
    __hip_bfloat16* W1T    = (__hip_bfloat16*)(ws);                   // 1024 x 12544
    __hip_bfloat16* W2T    = (__hip_bfloat16*)(ws + 25690112);        // 1024 x 1024
    __hip_bfloat16* pooled = (__hip_bfloat16*)(ws + 27787264);        // 1024 x 12544
    __hip_bfloat16* part1  = (__hip_bfloat16*)(ws + 53477376);        // 14 x 1M bf16
    __hip_bfloat16* part2  = part1;                                   // alias
    __hip_bfloat16* featsT = (__hip_bfloat16*)(ws + 53477376);        // alias (dead before part1)
    __hip_bfloat16* A2     = (__hip_bfloat16*)(ws + 87031808);        // 1024 x 1024

    prep_kernel<<<1872, 512, 0, stream>>>(feats, W1, W2, featsT, W1T, W2T);
    roi_kernel4<<<2048, 256, 0, stream>>>(featsT, boxes, pooled);
    gemm1_8phase<<<256, 512, 0, stream>>>(pooled, W1T, part1);
    reduce_relu_kernel<<<512, 256, 0, stream>>>(part1, b1, A2, 14);
    gemm_bf16_kernel<<<dim3(8, 8, 4), 256, 0, stream>>>(A2, W2T, part2, 1024, 1024, 1024, 256);
    final_kernel<<<1024, 256, 0, stream>>>(part2, b2, boxes, bboxW, bboxb, g1, bb1, g2, bb2, out);
}

// Round 12
// 102.303 us; speedup vs baseline: 1.0565x; 1.0565x over previous
//
#include <hip/hip_runtime.h>
#include <hip/hip_bf16.h>

typedef __attribute__((ext_vector_type(8))) short short8;
typedef __attribute__((ext_vector_type(4))) float floatx4;

#define AS1(p) ((const __attribute__((address_space(1))) void*)(p))
#define AS3(p) ((__attribute__((address_space(3))) void*)(p))

__device__ __forceinline__ float bf_lo(unsigned u) { return __uint_as_float(u << 16); }
__device__ __forceinline__ float bf_hi(unsigned u) { return __uint_as_float(u & 0xffff0000u); }

// ---------------------------------------------------------------- 64x64 transpose tile body (R10-verified)
__device__ __forceinline__ void transpose_tile_64(
    const float* __restrict__ src, __hip_bfloat16* __restrict__ dst,
    size_t sstride, size_t dstride, float (*tile)[65], int t)
{
    const int lrow = t >> 5;
    const int lc2  = (t & 31) * 2;
    #pragma unroll
    for (int i = 0; i < 8; ++i) {
        const int sr = lrow + i * 8;
        const float2 v = *(const float2*)(src + (size_t)sr * sstride + lc2);
        tile[sr][lc2]     = v.x;
        tile[sr][lc2 + 1] = v.y;
    }
    __syncthreads();
    const int lane = t & 63, wave = t >> 6;
    const int c4 = (lane & 15) * 4;
    #pragma unroll
    for (int i = 0; i < 4; ++i) {
        const int d = wave * 16 + i * 4 + (lane >> 4);
        union { __hip_bfloat16 h[4]; uint2 u; } o;
        #pragma unroll
        for (int j = 0; j < 4; ++j)
            o.h[j] = __float2bfloat16(tile[c4 + j][d]);
        *(uint2*)(dst + (size_t)d * dstride + c4) = o.u;
    }
}

// ---------------------------------------------------------------- prep_feats: NCHW f32 -> NHWC bf16
__global__ __launch_bounds__(256) void prep_feats_kernel(
    const float* __restrict__ feats, __hip_bfloat16* __restrict__ featsT)
{
    __shared__ float tile[64][65];
    const int bid = blockIdx.x;
    const int b  = bid >> 10;
    const int r  = bid & 1023;
    const int ct = r >> 8;
    const int ht = r & 255;
    const float* src = feats + ((size_t)(b * 256 + ct * 64)) * 16384 + ht * 64;
    __hip_bfloat16* dst = featsT + ((size_t)b * 16384 + ht * 64) * 256 + ct * 64;
    transpose_tile_64(src, dst, 16384, 256, tile, threadIdx.x);
}

// ---------------------------------------------------------------- roi_fused: ROI align + W1/W2 transpose
// blocks [0,2048): roi (latency/L2-bound); [2048,5184): W1 permute; [5184,5440): W2 transpose (HBM-bound).
__global__ __launch_bounds__(256) void roi_fused_kernel(
    const __hip_bfloat16* __restrict__ featsT, const float* __restrict__ boxes,
    __hip_bfloat16* __restrict__ pooled,
    const float* __restrict__ W1, const float* __restrict__ W2,
    __hip_bfloat16* __restrict__ W1T, __hip_bfloat16* __restrict__ W2T)
{
    __shared__ float tile[64][65];
    __shared__ int   sy0[14], sy1[14], sx0[14], sx1[14];
    __shared__ float sly[14], svy[14], slx[14], svx[14];
    const int tid = threadIdx.x;

    if (blockIdx.x >= 2048) {
        int r = blockIdx.x - 2048;
        const float* src;
        __hip_bfloat16* dst;
        size_t sstride, dstride;
        if (r < 3136) {
            const int bin = r / 64;
            r -= bin * 64;
            const int ct = r >> 4;
            const int nt = r & 15;
            src = W1  + ((size_t)(ct * 64) * 49 + bin) * 1024 + nt * 64;
            sstride = 49 * 1024;
            dst = W1T + (size_t)(nt * 64) * 12544 + bin * 256 + ct * 64;
            dstride = 12544;
        } else {
            r -= 3136;
            const int rt = r >> 4, ct2 = r & 15;
            src = W2  + (size_t)(rt * 64) * 1024 + ct2 * 64;
            sstride = 1024;
            dst = W2T + (size_t)(ct2 * 64) * 1024 + rt * 64;
            dstride = 1024;
        }
        transpose_tile_64(src, dst, sstride, dstride, tile, tid);
        return;
    }

    // ---- ROI branch (identical to roi_kernel4)
    const int bn   = blockIdx.x >> 1;
    const int half = blockIdx.x & 1;
    if (tid < 28) {
        const int  i   = tid % 14;
        const bool isx = tid >= 14;
        const float lo = boxes[bn * 4 + (isx ? 0 : 1)] * 0.25f;
        const float hi = boxes[bn * 4 + (isx ? 2 : 3)] * 0.25f;
        const float szb = fmaxf(hi - lo, 1.0f) * (1.0f / 7.0f);
        const float coord = lo + szb * ((i + 0.5f) * 0.5f);
        const float valid = (coord > -1.0f && coord < 128.0f) ? 1.0f : 0.0f;
        const float cc = fminf(fmaxf(coord, 0.0f), 127.0f);
        const int i0 = (int)floorf(cc);
        const int i1 = min(i0 + 1, 127);
        const float l = cc - (float)i0;
        if (isx) { sx0[i] = i0; sx1[i] = i1; slx[i] = l; svx[i] = valid; }
        else     { sy0[i] = i0; sy1[i] = i1; sly[i] = l; svy[i] = valid; }
    }
    __syncthreads();
    const int wave = tid >> 6;
    const int lane = tid & 63;
    const int sub  = lane >> 5;
    const int co   = lane & 31;
    const int b    = bn >> 8;
    const __hip_bfloat16* fb = featsT + (size_t)b * 4194304 + co * 8;
    __hip_bfloat16* po = pooled + (size_t)bn * 12544 + co * 8;

    const int pstart = (half ? 12 : 0) + wave;
    const int pend   = half ? 25 : 12;
    for (int p = pstart; p < pend; p += 4) {
        int bin = 2 * p + sub;
        if (bin > 48) bin = 48;
        const int ph = (bin * 37) >> 8;
        const int pw = bin - ph * 7;
        float s0 = 0.f, s1 = 0.f, s2 = 0.f, s3 = 0.f;
        float s4 = 0.f, s5 = 0.f, s6 = 0.f, s7 = 0.f;
        #pragma unroll
        for (int sy = 0; sy < 2; ++sy) {
            const int iy = ph * 2 + sy;
            const int y0 = sy0[iy], y1 = sy1[iy];
            const float ly = sly[iy], wy = svy[iy];
            const float hy = 1.f - ly;
            #pragma unroll
            for (int sx = 0; sx < 2; ++sx) {
                const int ix = pw * 2 + sx;
                const int x0 = sx0[ix], x1 = sx1[ix];
                const float lx = slx[ix], wx = svx[ix];
                const float hx = 1.f - lx;
                const uint4 u00 = *(const uint4*)(fb + (((y0 << 7) + x0) * 256));
                const uint4 u01 = *(const uint4*)(fb + (((y0 << 7) + x1) * 256));
                const uint4 u10 = *(const uint4*)(fb + (((y1 << 7) + x0) * 256));
                const uint4 u11 = *(const uint4*)(fb + (((y1 << 7) + x1) * 256));
                const float wv  = wy * wx;
                const float w00 = hy * hx * wv, w01 = hy * lx * wv;
                const float w10 = ly * hx * wv, w11 = ly * lx * wv;
                s0 += w00 * bf_lo(u00.x) + w01 * bf_lo(u01.x) + w10 * bf_lo(u10.x) + w11 * bf_lo(u11.x);
                s1 += w00 * bf_hi(u00.x) + w01 * bf_hi(u01.x) + w10 * bf_hi(u10.x) + w11 * bf_hi(u11.x);
                s2 += w00 * bf_lo(u00.y) + w01 * bf_lo(u01.y) + w10 * bf_lo(u10.y) + w11 * bf_lo(u11.y);
                s3 += w00 * bf_hi(u00.y) + w01 * bf_hi(u01.y) + w10 * bf_hi(u10.y) + w11 * bf_hi(u11.y);
                s4 += w00 * bf_lo(u00.z) + w01 * bf_lo(u01.z) + w10 * bf_lo(u10.z) + w11 * bf_lo(u11.z);
                s5 += w00 * bf_hi(u00.z) + w01 * bf_hi(u01.z) + w10 * bf_hi(u10.z) + w11 * bf_hi(u11.z);
                s6 += w00 * bf_lo(u00.w) + w01 * bf_lo(u01.w) + w10 * bf_lo(u10.w) + w11 * bf_lo(u11.w);
                s7 += w00 * bf_hi(u00.w) + w01 * bf_hi(u01.w) + w10 * bf_hi(u10.w) + w11 * bf_hi(u11.w);
            }
        }
        union { __hip_bfloat16 h[8]; uint4 u; } o;
        o.h[0] = __float2bfloat16(s0 * 0.25f);
        o.h[1] = __float2bfloat16(s1 * 0.25f);
        o.h[2] = __float2bfloat16(s2 * 0.25f);
        o.h[3] = __float2bfloat16(s3 * 0.25f);
        o.h[4] = __float2bfloat16(s4 * 0.25f);
        o.h[5] = __float2bfloat16(s5 * 0.25f);
        o.h[6] = __float2bfloat16(s6 * 0.25f);
        o.h[7] = __float2bfloat16(s7 * 0.25f);
        *(uint4*)(po + bin * 256) = o.u;
    }
}

// ---------------------------------------------------------------- GEMM1: 256x256 tile, 8-phase,
// 3-bit XOR swizzle, XCD-exact z-map, vmcnt(4) before certifying barriers (phases 4/8).
__global__ __launch_bounds__(512, 2) void gemm1_8phase(
    const __hip_bfloat16* __restrict__ A,
    const __hip_bfloat16* __restrict__ BT,
    __hip_bfloat16* __restrict__ Cpart)
{
    constexpr int K = 12544;
    constexpr int KCHUNK = 896;
    constexpr int NKT = 14;
    constexpr int ITERS = 7;

    __shared__ char lds[131072];

    const int bid = blockIdx.x;
    const int xcd = bid & 7;
    const int sl  = bid >> 3;
    const int z   = xcd + 8 * (sl >> 4);
    if (z >= 14) return;
    const int tile = sl & 15;
    const int by = tile >> 2, bx = tile & 3;
    const int m0 = by << 8, n0 = bx << 8;
    const int k0 = z * KCHUNK;

    const int tid  = threadIdx.x;
    const int lane = tid & 63;
    const int wave = tid >> 6;
    const int wm   = wave >> 2;
    const int wn   = wave & 3;
    const int l15  = lane & 15;
    const int kq   = (lane >> 4) << 3;

    floatx4 acc[8][4] = {};
    short8 bf[4][2];

    auto stage = [&](const __hip_bfloat16* gsrc, int ldsoff) {
        #pragma unroll
        for (int j = 0; j < 2; ++j) {
            const int lin = j * 8192 + tid * 16;
            const int r   = lin >> 7;
            const int cs  = ((lin & 127) ^ ((r & 7) << 4)) >> 1;
            __builtin_amdgcn_global_load_lds(AS1(gsrc + (size_t)r * K + cs),
                                             AS3(lds + ldsoff + lin), 16, 0, 0);
        }
    };

#define PHASE(SLOT, MQ, FIRSTB, STAGE_STMT, VM)                                    \
    {                                                                               \
        if (FIRSTB) {                                                               \
            _Pragma("unroll")                                                       \
            for (int nf = 0; nf < 4; ++nf) {                                        \
                const int nl = wn * 64 + nf * 16 + l15;                             \
                const int bh = nl >> 7, br = nl & 127;                              \
                _Pragma("unroll")                                                   \
                for (int ks = 0; ks < 2; ++ks)                                      \
                    bf[nf][ks] = *(const short8*)(lds + (SLOT) * 65536 + 32768      \
                        + bh * 16384 + br * 128                                     \
                        + (((ks * 32 + kq) * 2) ^ ((br & 7) << 4)));                \
            }                                                                       \
        }                                                                           \
        short8 af[2][2];                                                            \
        _Pragma("unroll")                                                           \
        for (int mf = 0; mf < 2; ++mf) {                                            \
            const int ar = (MQ) * 32 + mf * 16 + l15;                               \
            _Pragma("unroll")                                                       \
            for (int ks = 0; ks < 2; ++ks)                                          \
                af[mf][ks] = *(const short8*)(lds + (SLOT) * 65536 + wm * 16384     \
                    + ar * 128 + (((ks * 32 + kq) * 2) ^ ((ar & 7) << 4)));         \
        }                                                                           \
        STAGE_STMT;                                                                 \
        __builtin_amdgcn_s_barrier();                                               \
        asm volatile("s_waitcnt lgkmcnt(0)" ::: "memory");                          \
        __builtin_amdgcn_s_setprio(1);                                              \
        _Pragma("unroll")                                                           \
        for (int mf = 0; mf < 2; ++mf)                                              \
            _Pragma("unroll")                                                       \
            for (int nf = 0; nf < 4; ++nf)                                          \
                _Pragma("unroll")                                                   \
                for (int ks = 0; ks < 2; ++ks)                                      \
                    acc[(MQ) * 2 + mf][nf] = __builtin_amdgcn_mfma_f32_16x16x32_bf16( \
                        af[mf][ks], bf[nf][ks], acc[(MQ) * 2 + mf][nf], 0, 0, 0);   \
        __builtin_amdgcn_s_setprio(0);                                              \
        if (VM) asm volatile("s_waitcnt vmcnt(4)" ::: "memory");                    \
        __builtin_amdgcn_s_barrier();                                               \
    }

    stage(BT + (size_t)n0 * K + k0,               32768);
    stage(BT + (size_t)(n0 + 128) * K + k0,       32768 + 16384);
    stage(A  + (size_t)m0 * K + k0,               0);
    stage(A  + (size_t)(m0 + 128) * K + k0,       16384);
    stage(BT + (size_t)n0 * K + k0 + 64,          65536 + 32768);
    stage(BT + (size_t)(n0 + 128) * K + k0 + 64,  65536 + 32768 + 16384);
    asm volatile("s_waitcnt vmcnt(4)" ::: "memory");
    __builtin_amdgcn_s_barrier();

    for (int it = 0; it < ITERS; ++it) {
        const int t1 = 2 * it + 1;
        int t2 = 2 * it + 2; if (t2 > NKT - 1) t2 = NKT - 1;
        int t3 = 2 * it + 3; if (t3 > NKT - 1) t3 = NKT - 1;
        PHASE(0, 0, true,  stage(A  + (size_t)m0 * K + k0 + t1 * 64,          65536),          0);
        PHASE(0, 1, false, stage(A  + (size_t)(m0 + 128) * K + k0 + t1 * 64,  65536 + 16384),  0);
        PHASE(0, 2, false, stage(BT + (size_t)n0 * K + k0 + t2 * 64,          32768),          0);
        PHASE(0, 3, false, stage(BT + (size_t)(n0 + 128) * K + k0 + t2 * 64,  32768 + 16384),  1);
        PHASE(1, 0, true,  stage(A  + (size_t)m0 * K + k0 + t2 * 64,          0),              0);
        PHASE(1, 1, false, stage(A  + (size_t)(m0 + 128) * K + k0 + t2 * 64,  16384),          0);
        PHASE(1, 2, false, stage(BT + (size_t)n0 * K + k0 + t3 * 64,          65536 + 32768),  0);
        PHASE(1, 3, false, stage(BT + (size_t)(n0 + 128) * K + k0 + t3 * 64,  65536 + 32768 + 16384), 1);
    }
#undef PHASE

    __hip_bfloat16* cp = Cpart + (size_t)z * (1024 * 1024) + (size_t)m0 * 1024 + n0;
    const int r4 = (lane >> 4) << 2;
    #pragma unroll
    for (int mi = 0; mi < 8; ++mi)
        #pragma unroll
        for (int nf = 0; nf < 4; ++nf)
            #pragma unroll
            for (int r = 0; r < 4; ++r)
                cp[(size_t)(wm * 128 + mi * 16 + r4 + r) * 1024 + wn * 64 + nf * 16 + l15] =
                    __float2bfloat16(acc[mi][nf][r]);
}

// ---------------------------------------------------------------- 128^2 GEMM (GEMM2), swizzled LDS
__global__ __launch_bounds__(256) void gemm_bf16_kernel(
    const __hip_bfloat16* __restrict__ A,
    const __hip_bfloat16* __restrict__ BT,
    __hip_bfloat16* __restrict__ Cpart,
    int Mdim, int Ndim, int K, int kChunk)
{
    __shared__ __hip_bfloat16 lsA[128 * 64];
    __shared__ __hip_bfloat16 lsB[128 * 64];
    const int tid  = threadIdx.x;
    const int lane = tid & 63;
    const int wave = tid >> 6;
    const int wrow = (wave >> 1) << 6;
    const int wcol = (wave & 1) << 6;
    const int m0 = blockIdx.y << 7;
    const int n0 = blockIdx.x << 7;
    const int k0 = blockIdx.z * kChunk;

    floatx4 acc[4][4] = {};

    const int strow = tid >> 3;
    const int scol  = ((tid & 7) ^ (strow & 7)) << 3;
    const __hip_bfloat16* aSrc = A  + (size_t)(m0 + strow) * K + k0 + scol;
    const __hip_bfloat16* bSrc = BT + (size_t)(n0 + strow) * K + k0 + scol;
    __hip_bfloat16* ldsA = lsA + tid * 8;
    __hip_bfloat16* ldsB = lsB + tid * 8;
    const size_t rowJump = (size_t)32 * K;

    const int row16 = lane & 15;
    const int kg    = (lane >> 4) << 3;
    const int nk = kChunk >> 6;
    for (int kk = 0; kk < nk; ++kk) {
        __syncthreads();
        #pragma unroll
        for (int g = 0; g < 4; ++g) {
            __builtin_amdgcn_global_load_lds(AS1(aSrc + g * rowJump), AS3(ldsA + g * 2048), 16, 0, 0);
            __builtin_amdgcn_global_load_lds(AS1(bSrc + g * rowJump), AS3(ldsB + g * 2048), 16, 0, 0);
        }
        __syncthreads();
        #pragma unroll
        for (int ks = 0; ks < 2; ++ks) {
            short8 af[4], bfr[4];
            #pragma unroll
            for (int m = 0; m < 4; ++m) {
                const int ar = wrow + m * 16 + row16;
                af[m] = *(const short8*)(lsA + ar * 64 + ((ks * 32 + kg) ^ ((ar & 7) << 3)));
            }
            #pragma unroll
            for (int n = 0; n < 4; ++n) {
                const int br = wcol + n * 16 + row16;
                bfr[n] = *(const short8*)(lsB + br * 64 + ((ks * 32 + kg) ^ ((br & 7) << 3)));
            }
            #pragma unroll
            for (int m = 0; m < 4; ++m)
                #pragma unroll
                for (int n = 0; n < 4; ++n)
                    acc[m][n] = __builtin_amdgcn_mfma_f32_16x16x32_bf16(af[m], bfr[n], acc[m][n], 0, 0, 0);
        }
        aSrc += 64; bSrc += 64;
    }
    __hip_bfloat16* cp = Cpart + (size_t)blockIdx.z * Mdim * Ndim + (size_t)m0 * Ndim + n0;
    const int r4 = (lane >> 4) << 2;
    #pragma unroll
    for (int m = 0; m < 4; ++m)
        #pragma unroll
        for (int n = 0; n < 4; ++n)
            #pragma unroll
            for (int r = 0; r < 4; ++r)
                cp[(size_t)(wrow + m * 16 + r4 + r) * Ndim + (wcol + n * 16 + row16)] =
                    __float2bfloat16(acc[m][n][r]);
}

// ---------------------------------------------------------------- splitK reduce + bias + ReLU -> bf16
__global__ __launch_bounds__(256) void reduce_relu_kernel(
    const __hip_bfloat16* __restrict__ part, const float* __restrict__ bias,
    __hip_bfloat16* __restrict__ out, int nsplit)
{
    const size_t MN = 1024 * 1024;
    const int idx = (blockIdx.x * 256 + threadIdx.x) * 8;
    float s[8] = {};
    for (int z = 0; z < nsplit; ++z) {
        const uint4 v = *(const uint4*)(part + z * MN + idx);
        s[0] += bf_lo(v.x); s[1] += bf_hi(v.x);
        s[2] += bf_lo(v.y); s[3] += bf_hi(v.y);
        s[4] += bf_lo(v.z); s[5] += bf_hi(v.z);
        s[6] += bf_lo(v.w); s[7] += bf_hi(v.w);
    }
    const int jb = idx & 1023;
    const floatx4 b0 = *(const floatx4*)(bias + jb);
    const floatx4 b1v = *(const floatx4*)(bias + jb + 4);
    union { __hip_bfloat16 h[8]; uint4 u; } o;
    #pragma unroll
    for (int i = 0; i < 4; ++i) {
        const float v0 = s[i] + b0[i];
        o.h[i] = __float2bfloat16(v0 > 0.0f ? v0 : 0.0f);
    }
    #pragma unroll
    for (int i = 0; i < 4; ++i) {
        const float v1 = s[4 + i] + b1v[i];
        o.h[4 + i] = __float2bfloat16(v1 > 0.0f ? v1 : 0.0f);
    }
    *(uint4*)(out + idx) = o.u;
}

// ---------------------------------------------------------------- block LN stats
__device__ inline void block_stats(float s, float ss, float* red, float& mean, float& rstd)
{
    #pragma unroll
    for (int o = 32; o > 0; o >>= 1) {
        s  += __shfl_down(s, o, 64);
        ss += __shfl_down(ss, o, 64);
    }
    const int wave = threadIdx.x >> 6;
    const int lane = threadIdx.x & 63;
    __syncthreads();
    if (lane == 0) { red[wave] = s; red[8 + wave] = ss; }
    __syncthreads();
    const float a = red[0] + red[1] + red[2] + red[3];
    const float b = red[8] + red[9] + red[10] + red[11];
    mean = a * (1.0f / 1024.0f);
    const float var = b * (1.0f / 1024.0f) - mean * mean;
    rstd = rsqrtf(var + 1e-5f);
}

// ---------------------------------------------------------------- splitK reduce2 (bf16) + bbox path + 2x LN
__global__ __launch_bounds__(256) void final_kernel(
    const __hip_bfloat16* __restrict__ part2, const float* __restrict__ b2,
    const float* __restrict__ boxes,
    const float* __restrict__ bboxW, const float* __restrict__ bboxb,
    const float* __restrict__ g1, const float* __restrict__ bb1,
    const float* __restrict__ g2, const float* __restrict__ bb2,
    float* __restrict__ out)
{
    __shared__ float red[16];
    const int row = blockIdx.x;
    const int j0 = threadIdx.x * 4;
    const size_t MN = 1024 * 1024;

    floatx4 h = *(const floatx4*)(b2 + j0);
    #pragma unroll
    for (int z = 0; z < 4; ++z) {
        const uint2 v = *(const uint2*)(part2 + z * MN + (size_t)row * 1024 + j0);
        h[0] += bf_lo(v.x); h[1] += bf_hi(v.x);
        h[2] += bf_lo(v.y); h[3] += bf_hi(v.y);
    }

    const float sc = 0.25f / 128.0f;
    const float nb0 = boxes[row * 4 + 0] * sc;
    const float nb1 = boxes[row * 4 + 1] * sc;
    const float nb2 = boxes[row * 4 + 2] * sc;
    const float nb3 = boxes[row * 4 + 3] * sc;

    floatx4 p = *(const floatx4*)(bboxb + j0);
    p += nb0 * *(const floatx4*)(bboxW + j0);
    p += nb1 * *(const floatx4*)(bboxW + 1024 + j0);
    p += nb2 * *(const floatx4*)(bboxW + 2048 + j0);
    p += nb3 * *(const floatx4*)(bboxW + 3072 + j0);

    float mean, rstd;
    block_stats(p[0] + p[1] + p[2] + p[3],
                p[0]*p[0] + p[1]*p[1] + p[2]*p[2] + p[3]*p[3], red, mean, rstd);
    const floatx4 pg = *(const floatx4*)(g1 + j0);
    const floatx4 pb = *(const floatx4*)(bb1 + j0);
    floatx4 x;
    #pragma unroll
    for (int i = 0; i < 4; ++i)
        x[i] = h[i] + ((p[i] - mean) * rstd * pg[i] + pb[i]);

    block_stats(x[0] + x[1] + x[2] + x[3],
                x[0]*x[0] + x[1]*x[1] + x[2]*x[2] + x[3]*x[3], red, mean, rstd);
    const floatx4 og = *(const floatx4*)(g2 + j0);
    const floatx4 ob = *(const floatx4*)(bb2 + j0);
    floatx4 o;
    #pragma unroll
    for (int i = 0; i < 4; ++i)
        o[i] = (x[i] - mean) * rstd * og[i] + ob[i];
    *(floatx4*)(out + (size_t)row * 1024 + j0) = o;
}

// ---------------------------------------------------------------- launch
extern "C" void kernel_launch(void* const* d_in, const int* in_sizes, int n_in,
                              void* d_out, int out_size, void* d_ws, size_t ws_size,
                              hipStream_t stream)
{
    const float* feats = (const float*)d_in[0];
    const float* boxes = (const float*)d_in[1];
    const float* W1    = (const float*)d_in[3];
    const float* b1    = (const float*)d_in[4];
    const float* W2    = (const float*)d_in[5];
    const float* b2    = (const float*)d_in[6];
    const float* bboxW = (const float*)d_in[7];
    const float* bboxb = (const float*)d_in[8];
    const float* g1    = (const float*)d_in[9];
    const float* bb1   = (const float*)d_in[10];
    const float* g2    = (const float*)d_in[11];
    const float* bb2   = (const float*)d_in[12];
    float* out = (float*)d_out;

    char* ws = (char*)d_ws;
    __hip_bfloat16* W1T    = (__hip_bfloat16*)(ws);                   // 1024 x 12544
    __hip_bfloat16* W2T    = (__hip_bfloat16*)(ws + 25690112);        // 1024 x 1024
    __hip_bfloat16* pooled = (__hip_bfloat16*)(ws + 27787264);        // 1024 x 12544
    __hip_bfloat16* part1  = (__hip_bfloat16*)(ws + 53477376);        // 14 x 1M bf16
    __hip_bfloat16* part2  = part1;                                   // alias
    __hip_bfloat16* featsT = (__hip_bfloat16*)(ws + 53477376);        // alias (dead before part1)
    __hip_bfloat16* A2     = (__hip_bfloat16*)(ws + 87031808);        // 1024 x 1024

    prep_feats_kernel<<<4096, 256, 0, stream>>>(feats, featsT);
    roi_fused_kernel<<<5440, 256, 0, stream>>>(featsT, boxes, pooled, W1, W2, W1T, W2T);
    gemm1_8phase<<<256, 512, 0, stream>>>(pooled, W1T, part1);
    reduce_relu_kernel<<<512, 256, 0, stream>>>(part1, b1, A2, 14);
    gemm_bf16_kernel<<<dim3(8, 8, 4), 256, 0, stream>>>(A2, W2T, part2, 1024, 1024, 1024, 256);
    final_kernel<<<1024, 256, 0, stream>>>(part2, b2, boxes, bboxW, bboxb, g1, bb1, g2, bb2, out);
}